// Round 6
// baseline (484.803 us; speedup 1.0000x reference)
//
#include <hip/hip_runtime.h>

#define S_LEN 2048
#define NH 32
#define NKV 8
#define HEADD 64
#define DMODEL 2048
#define NQKV 3072

typedef float f32x4 __attribute__((ext_vector_type(4)));
typedef float f32x16 __attribute__((ext_vector_type(16)));
typedef short s16x8 __attribute__((ext_vector_type(8)));
typedef int   i32x4 __attribute__((ext_vector_type(4)));
typedef unsigned short u16;
typedef u16 u16x4 __attribute__((ext_vector_type(4)));

__device__ __forceinline__ float b2f(u16 u) {
  unsigned int x = ((unsigned int)u) << 16;
  float f;
  __builtin_memcpy(&f, &x, 4);
  return f;
}
__device__ __forceinline__ u16 f2b(float f) {
  unsigned int x;
  __builtin_memcpy(&x, &f, 4);
  unsigned int r = x + 0x7fffu + ((x >> 16) & 1u);
  return (u16)(r >> 16);
}
__device__ __forceinline__ unsigned fbits(float f) {
  unsigned x; __builtin_memcpy(&x, &f, 4); return x;
}

// async 16B/lane global -> LDS (LDS dest is wave-uniform base + lane*16)
__device__ __forceinline__ void gload_lds16(const u16* g, u16* l) {
  __builtin_amdgcn_global_load_lds((const __attribute__((address_space(1))) void*)g,
                                   (__attribute__((address_space(3))) void*)l, 16, 0, 0);
}

template<int N> __device__ __forceinline__ void wait_vm() {
  asm volatile("s_waitcnt vmcnt(%0)" :: "n"(N) : "memory");
}

// ---------- x fp32 -> bf16 ----------
__global__ void cast_x_kernel(const float* __restrict__ src, u16* __restrict__ dst) {
  int i = (blockIdx.x * 256 + threadIdx.x) * 4;
  f32x4 v = *(const f32x4*)(src + i);
  u16x4 o;
  o[0] = f2b(v[0]); o[1] = f2b(v[1]); o[2] = f2b(v[2]); o[3] = f2b(v[3]);
  *(u16x4*)(dst + i) = o;
}

// ---------- transpose + cast: src (K x N fp32) -> dst (N x K bf16) ----------
__global__ void transpose_cast(const float* __restrict__ src, u16* __restrict__ dst, int N, int K) {
  __shared__ float tile[32][33];
  int n0 = blockIdx.x * 32, k0 = blockIdx.y * 32;
  int tx = threadIdx.x, ty = threadIdx.y;  // (32, 8)
#pragma unroll
  for (int i = 0; i < 32; i += 8)
    tile[ty + i][tx] = src[(size_t)(k0 + ty + i) * N + n0 + tx];
  __syncthreads();
#pragma unroll
  for (int i = 0; i < 32; i += 8)
    dst[(size_t)(n0 + ty + i) * K + k0 + tx] = f2b(tile[tx][ty + i]);
}

// ---------- GEMM: 256-row tiles, 8 waves, 4-buffer counted-vmcnt pipeline ----------
// C(MxN) = A(MxK=2048) * Bt(NxK=2048)^T, bf16. BM=256, BN template (256 or 128).
// Per K32-step: wait vmcnt(2L) -> raw s_barrier -> stage step+3 -> ds_read -> 8xNF MFMA.
#define PIPE_BODY(Q, STAGE, VMN)                                                   \
  {                                                                                \
    wait_vm<VMN>();                                                                \
    __builtin_amdgcn_s_barrier();                                                  \
    __builtin_amdgcn_sched_barrier(0);                                             \
    if (STAGE) {                                                                   \
      u16* db = sm + ((Q + 3) & 3) * BUFE;                                         \
      gload_lds16(gA0, db + w * 1024);                                             \
      gload_lds16(gA1, db + w * 1024 + 512);                                       \
      if (BN == 256) {                                                             \
        gload_lds16(gB0, db + ABUF + w * 1024);                                    \
        gload_lds16(gB1, db + ABUF + w * 1024 + 512);                              \
      } else {                                                                     \
        gload_lds16(gB0, db + ABUF + w * 512);                                     \
      }                                                                            \
      gA0 += 32; gA1 += 32; gB0 += 32; if (BN == 256) gB1 += 32;                   \
    }                                                                              \
    const u16* bb = sm + Q * BUFE;                                                 \
    s16x8 af[8], bf[NF];                                                           \
    _Pragma("unroll") for (int i = 0; i < 8; i++)  af[i] = *(const s16x8*)(bb + aoff[i]); \
    _Pragma("unroll") for (int j = 0; j < NF; j++) bf[j] = *(const s16x8*)(bb + boff[j]); \
    __builtin_amdgcn_s_setprio(1);                                                 \
    _Pragma("unroll") for (int mi = 0; mi < 8; mi++)                               \
      _Pragma("unroll") for (int ni = 0; ni < NF; ni++)                            \
        acc[mi][ni] = __builtin_amdgcn_mfma_f32_16x16x32_bf16(af[mi], bf[ni], acc[mi][ni], 0, 0, 0); \
    __builtin_amdgcn_s_setprio(0);                                                 \
  }

template<int BN>
__global__ __launch_bounds__(512, 2) void gemm_pipe(
    const u16* __restrict__ A, const u16* __restrict__ Bt, void* __restrict__ Cout,
    int M, int N, int writeF32) {
  extern __shared__ __align__(16) u16 sm[];
  constexpr int NF   = BN / 64;        // n-frags per wave (4 or 2)
  constexpr int ABUF = 256 * 32;       // 8192 elems per buffer (A)
  constexpr int BUFE = ABUF + BN * 32; // elems per buffer (A+B)
  constexpr int LPS  = 2 + BN / 128;   // gloads per wave per step (4 or 3)

  int nb = N / BN;
  int nwg = (M >> 8) * nb;             // 192 or 256: both % 8 == 0
  int cpx = nwg >> 3;
  int bid = ((int)blockIdx.x & 7) * cpx + ((int)blockIdx.x >> 3);  // XCD swizzle
  int m0 = (bid / nb) << 8;
  int n0 = (bid % nb) * BN;

  int tid = threadIdx.x;
  int lane = tid & 63;
  int w = tid >> 6;                    // 0..7
  int wm8 = (w >> 2) << 7;             // 0 / 128
  int wn8 = (w & 3) * (BN / 4);
  int l15 = lane & 15;
  int quad = lane >> 4;

  // staging source addresses (pre-swizzled global, linear LDS dest)
  int lr = lane >> 3;
  int lc = lane & 7;
  int slot = lc ^ lr;
  int kc8 = (slot & 3) << 3;
  const u16* gA0 = A + (size_t)(m0 + w * 32 + (lr << 1) + (slot >> 2)) * 2048 + kc8;
  const u16* gA1 = gA0 + (size_t)16 * 2048;
  const u16* gB0;
  const u16* gB1;
  if (BN == 256) {
    gB0 = Bt + (size_t)(n0 + w * 32 + (lr << 1) + (slot >> 2)) * 2048 + kc8;
    gB1 = gB0 + (size_t)16 * 2048;
  } else {
    gB0 = Bt + (size_t)(n0 + w * 16 + (lr << 1) + (slot >> 2)) * 2048 + kc8;
    gB1 = gB0;
  }

  // fragment ds_read offsets (elements), swizzled
  int rb = l15 >> 1;
  int sl = (((((l15 & 1) << 2) | quad) ^ rb)) << 3;
  int rbase = rb * 64 + sl;
  int aoff[8], boff[NF];
#pragma unroll
  for (int i = 0; i < 8; i++) aoff[i] = wm8 * 32 + i * 512 + rbase;
#pragma unroll
  for (int j = 0; j < NF; j++) boff[j] = ABUF + wn8 * 32 + j * 512 + rbase;

  f32x4 acc[8][NF] = {};

  // prologue: stage steps 0,1,2 into bufs 0,1,2
#pragma unroll
  for (int pt = 0; pt < 3; pt++) {
    u16* db = sm + pt * BUFE;
    gload_lds16(gA0, db + w * 1024);
    gload_lds16(gA1, db + w * 1024 + 512);
    if (BN == 256) {
      gload_lds16(gB0, db + ABUF + w * 1024);
      gload_lds16(gB1, db + ABUF + w * 1024 + 512);
    } else {
      gload_lds16(gB0, db + ABUF + w * 512);
    }
    gA0 += 32; gA1 += 32; gB0 += 32; if (BN == 256) gB1 += 32;
  }

#pragma unroll 1
  for (int it = 0; it < 15; ++it) {
    PIPE_BODY(0, 1, 2 * LPS)
    PIPE_BODY(1, 1, 2 * LPS)
    PIPE_BODY(2, 1, 2 * LPS)
    PIPE_BODY(3, 1, 2 * LPS)
  }
  PIPE_BODY(0, 1, 2 * LPS)
  PIPE_BODY(1, 0, 2 * LPS)
  PIPE_BODY(2, 0, LPS)
  PIPE_BODY(3, 0, 0)

#pragma unroll
  for (int mi = 0; mi < 8; mi++)
#pragma unroll
    for (int ni = 0; ni < NF; ni++)
#pragma unroll
      for (int r = 0; r < 4; r++) {
        int row = m0 + wm8 + mi * 16 + (quad << 2) + r;
        int col = n0 + wn8 + ni * 16 + l15;
        float v = acc[mi][ni][r];
        if (writeF32) ((float*)Cout)[(size_t)row * N + col] = v;
        else ((u16*)Cout)[(size_t)row * N + col] = f2b(v);
      }
}

// ---------- in-place RoPE on q (scaled by 0.125*log2e -> base-2 softmax domain) and k ----------
__global__ void rope_kernel(u16* __restrict__ qkv) {
  int row = blockIdx.x;
  int s = row & (S_LEN - 1);
  u16* p = qkv + (size_t)row * NQKV;
  int t = threadIdx.x;
  int d = t & 31;
  int hh = t >> 5;
  float inv_freq = exp2f(-(float)d * (13.287712379549449f / 32.0f));
  float ang = (float)s * inv_freq;
  float sn, cs;
  sincosf(ang, &sn, &cs);
  const float QSCALE = 0.18033688011112042f;  // 0.125 * log2(e)
#pragma unroll
  for (int i = 0; i < 4; i++) {
    int base = (hh + (i << 3)) * HEADD + d;
    float x1 = b2f(p[base]);
    float x2 = b2f(p[base + 32]);
    p[base]      = f2b((x1 * cs - x2 * sn) * QSCALE);
    p[base + 32] = f2b((x1 * sn + x2 * cs) * QSCALE);
  }
  {
    int base = DMODEL + hh * HEADD + d;
    float x1 = b2f(p[base]);
    float x2 = b2f(p[base + 32]);
    p[base]      = f2b(x1 * cs - x2 * sn);
    p[base + 32] = f2b(x1 * sn + x2 * cs);
  }
}

// ---------- V transpose: qkv v-slice -> Vt[b][g][d=64][s=2048] ----------
__global__ void vtrans_kernel(const u16* __restrict__ qkv, u16* __restrict__ Vt) {
  __shared__ __align__(16) u16 tile[64][72];
  int bid = blockIdx.x;  // 2*8*32 = 512
  int st = bid & 31;
  int g  = (bid >> 5) & 7;
  int b  = bid >> 8;
  int tid = threadIdx.x;
  int r = tid >> 2;
  int c = (tid & 3) << 4;
  const u16* src = qkv + (size_t)(b * S_LEN + st * 64 + r) * NQKV + 2560 + g * 64 + c;
  *(i32x4*)&tile[r][c]     = *(const i32x4*)src;
  *(i32x4*)&tile[r][c + 8] = *(const i32x4*)(src + 8);
  __syncthreads();
  u16* dst = Vt + (size_t)((b * 8 + g) * 64 + r) * S_LEN + st * 64 + c;
  u16 tmp[16];
#pragma unroll
  for (int j = 0; j < 16; j++) tmp[j] = tile[c + j][r];
  *(i32x4*)dst       = *(i32x4*)&tmp[0];
  *(i32x4*)(dst + 8) = *(i32x4*)&tmp[8];
}

// ---------- pack K & V into fragment-ordered tiles ----------
__global__ __launch_bounds__(64) void kvpack_kernel(const u16* __restrict__ qkv,
                                                    const u16* __restrict__ Vt,
                                                    u16* __restrict__ Kp,
                                                    u16* __restrict__ Vp) {
  int bid = blockIdx.x;  // 1024 = bg*64 + kb
  int kb = bid & 63;
  int bg = bid >> 6;
  int g = bg & 7;
  int b = bg >> 3;
  int lane = threadIdx.x;
  int l31 = lane & 31;
  int h2 = lane >> 5;

  const u16* kq = qkv + (size_t)(b * S_LEN + kb * 32 + l31) * NQKV + DMODEL + g * 64 + h2 * 8;
  u16* kdst = Kp + ((size_t)bid * 4) * 512 + lane * 8;
#pragma unroll
  for (int t = 0; t < 4; t++)
    *(i32x4*)(kdst + t * 512) = *(const i32x4*)(kq + t * 16);

  const u16* vq = Vt + (size_t)(bg * 64 + l31) * S_LEN + kb * 32 + h2 * 8;
  u16* vdst = Vp + ((size_t)bid * 4) * 512 + lane * 8;
  *(i32x4*)(vdst)        = *(const i32x4*)vq;
  *(i32x4*)(vdst + 512)  = *(const i32x4*)(vq + 16);
  *(i32x4*)(vdst + 1024) = *(const i32x4*)(vq + (size_t)32 * S_LEN);
  *(i32x4*)(vdst + 1536) = *(const i32x4*)(vq + (size_t)32 * S_LEN + 16);
}

// ---------- MFMA flash attention: pair-balanced + 2-wave k-split ----------
// Block j (of 2048) handles qb = 63-j/64... pair (63-pr, pr): 65 tiles total.
// TWO waves split each pass's k-range in half (softmax is additive without
// online-max: l = sum exp2(s), acc = sum exp2(s)*V), partials combined in LDS.
// => 4096 uniform-length waves = 4 waves/SIMD sustained, no drain tail.
__global__ __launch_bounds__(128, 4) void attn_kernel(const u16* __restrict__ qkv,
                                                      const u16* __restrict__ Kp,
                                                      const u16* __restrict__ Vp,
                                                      u16* __restrict__ out) {
  __shared__ float red[33 * 64];  // wave1 partials: 32 acc + 1 l per lane

  int bid = blockIdx.x;      // 2048 = pr(32) * 64
  int bh = bid & 63;
  int pr = bid >> 6;         // 0..31
  int h = bh & 31;
  int b = bh >> 5;
  int g = h >> 2;
  int bg = b * 8 + g;
  int tid = threadIdx.x;
  int wv = tid >> 6;         // 0 or 1
  int lane = tid & 63;
  int l31 = lane & 31;
  int h2 = lane >> 5;

  const u16* kp = Kp + ((size_t)bg * 64) * 2048 + lane * 8;
  const u16* vp = Vp + ((size_t)bg * 64) * 2048 + lane * 8;

#pragma unroll 1
  for (int pass = 0; pass < 2; ++pass) {
    int qb = pass ? pr : (63 - pr);
    int q0 = qb << 5;
    int nt = qb + 1;
    int h1 = (nt + 1) >> 1;          // wave0: [0,h1), wave1: [h1,nt)
    int k_lo = wv ? h1 : 0;
    int k_hi = wv ? nt : h1;

    const u16* qp = qkv + (size_t)(b * S_LEN + q0 + l31) * NQKV + h * HEADD + h2 * 8;
    s16x8 qf[4];
#pragma unroll
    for (int t = 0; t < 4; t++) qf[t] = *(const s16x8*)(qp + t * 16);

    float l_i = 0.f;
    f32x16 acc[2] = {};

    s16x8 kfa[4], vfa[4], kfb[4], vfb[4];

    auto loadkv = [&](int kb, s16x8 (&kf)[4], s16x8 (&vf)[4]) {
      const u16* kpp = kp + (size_t)kb * 2048;
      const u16* vpp = vp + (size_t)kb * 2048;
#pragma unroll
      for (int t = 0; t < 4; t++) {
        kf[t] = *(const s16x8*)(kpp + t * 512);
        vf[t] = *(const s16x8*)(vpp + t * 512);
      }
    };

    auto compute = [&](int kb, s16x8 (&kf)[4], s16x8 (&vf)[4]) {
      f32x16 sc = {};
      __builtin_amdgcn_s_setprio(1);
#pragma unroll
      for (int t = 0; t < 4; t++)
        sc = __builtin_amdgcn_mfma_f32_32x32x16_bf16(kf[t], qf[t], sc, 0, 0, 0);
      __builtin_amdgcn_s_setprio(0);

      float sv[16];
#pragma unroll
      for (int j = 0; j < 16; j++) sv[j] = sc[j];

      if (kb == qb) {
        int qg = q0 + l31;
#pragma unroll
        for (int j = 0; j < 16; j++) {
          int kg = kb * 32 + (j & 3) + ((j >> 2) << 3) + (h2 << 2);
          if (kg > qg) sv[j] = -1e30f;
        }
      }

      float e[16];
#pragma unroll
      for (int j = 0; j < 16; j++) e[j] = __builtin_amdgcn_exp2f(sv[j]);

      float ps = (((e[0] + e[1]) + (e[2] + e[3])) + ((e[4] + e[5]) + (e[6] + e[7])))
               + (((e[8] + e[9]) + (e[10] + e[11])) + ((e[12] + e[13]) + (e[14] + e[15])));
      ps += __shfl_xor(ps, 32);
      l_i += ps;

      unsigned Pk[8], Ex[8];
#pragma unroll
      for (int r = 0; r < 8; r++) {
        unsigned pk;
        asm("v_cvt_pk_bf16_f32 %0, %1, %2" : "=v"(pk) : "v"(e[2 * r]), "v"(e[2 * r + 1]));
        Pk[r] = pk;
      }
#pragma unroll
      for (int r = 0; r < 8; r++) Ex[r] = (unsigned)__shfl_xor((int)Pk[r], 32);

      unsigned B0u[4], B1u[4];
      B0u[0] = h2 ? Ex[2] : Pk[0];
      B0u[1] = h2 ? Ex[3] : Pk[1];
      B0u[2] = h2 ? Pk[2] : Ex[0];
      B0u[3] = h2 ? Pk[3] : Ex[1];
      B1u[0] = h2 ? Ex[6] : Pk[4];
      B1u[1] = h2 ? Ex[7] : Pk[5];
      B1u[2] = h2 ? Pk[6] : Ex[4];
      B1u[3] = h2 ? Pk[7] : Ex[5];
      s16x8 B0, B1;
      __builtin_memcpy(&B0, B0u, 16);
      __builtin_memcpy(&B1, B1u, 16);

      __builtin_amdgcn_s_setprio(1);
      acc[0] = __builtin_amdgcn_mfma_f32_32x32x16_bf16(vf[0], B0, acc[0], 0, 0, 0);
      acc[0] = __builtin_amdgcn_mfma_f32_32x32x16_bf16(vf[1], B1, acc[0], 0, 0, 0);
      acc[1] = __builtin_amdgcn_mfma_f32_32x32x16_bf16(vf[2], B0, acc[1], 0, 0, 0);
      acc[1] = __builtin_amdgcn_mfma_f32_32x32x16_bf16(vf[3], B1, acc[1], 0, 0, 0);
      __builtin_amdgcn_s_setprio(0);
    };

    if (k_lo < k_hi) {
      loadkv(k_lo, kfa, vfa);
      int kb = k_lo;
      while (true) {
        if (kb + 1 < k_hi) loadkv(kb + 1, kfb, vfb);
        compute(kb, kfa, vfa);
        if (++kb >= k_hi) break;
        if (kb + 1 < k_hi) loadkv(kb + 1, kfa, vfa);
        compute(kb, kfb, vfb);
        if (++kb >= k_hi) break;
      }
    }

    // combine the two waves' partial (acc, l) through LDS
    __syncthreads();   // wave0 finished reading red[] of the previous pass
    if (wv) {
#pragma unroll
      for (int dt = 0; dt < 2; dt++)
#pragma unroll
        for (int j = 0; j < 16; j++) red[(dt * 16 + j) * 64 + lane] = acc[dt][j];
      red[32 * 64 + lane] = l_i;
    }
    __syncthreads();
    if (!wv) {
#pragma unroll
      for (int dt = 0; dt < 2; dt++)
#pragma unroll
        for (int j = 0; j < 16; j++) acc[dt][j] += red[(dt * 16 + j) * 64 + lane];
      float linv = 1.0f / (l_i + red[32 * 64 + lane]);
      u16* op = out + (size_t)(b * S_LEN + q0 + l31) * DMODEL + h * HEADD;
#pragma unroll
      for (int dt = 0; dt < 2; dt++)
#pragma unroll
        for (int rg = 0; rg < 4; rg++) {
          u16x4 t4;
#pragma unroll
          for (int j = 0; j < 4; j++) t4[j] = f2b(acc[dt][rg * 4 + j] * linv);
          *(u16x4*)(op + dt * 32 + rg * 8 + h2 * 4) = t4;
        }
    }
  }
}

extern "C" void kernel_launch(void* const* d_in, const int* in_sizes, int n_in,
                              void* d_out, int out_size, void* d_ws, size_t ws_size,
                              hipStream_t stream) {
  const float* x  = (const float*)d_in[0];
  const float* wq = (const float*)d_in[1];
  const float* wk = (const float*)d_in[2];
  const float* wv = (const float*)d_in[3];
  const float* wo = (const float*)d_in[4];

  char* ws = (char*)d_ws;
  u16* xb    = (u16*)ws;                                   // 4096x2048 bf16 (16.8 MB)
  u16* wqkvT = (u16*)(ws + 16777216);                      // 3072x2048 (12.6 MB)
  u16* woT   = (u16*)(ws + 16777216 + 12582912);           // 2048x2048 (8.4 MB)
  u16* qkv   = (u16*)(ws + 16777216 + 12582912 + 8388608); // 4096x3072 (25.2 MB)
  u16* attnb = xb;                                  // xb dead after gemm1
  u16* Vt    = wqkvT;                               // wqkvT region reused after gemm1
  u16* Kp    = (u16*)(ws + 16777216 + 4194304);
  u16* Vp    = (u16*)(ws + 16777216 + 8388608);

  // allow >64KB dynamic LDS for the pipelined GEMMs
  hipFuncSetAttribute(reinterpret_cast<const void*>(gemm_pipe<256>),
                      hipFuncAttributeMaxDynamicSharedMemorySize, 131072);
  hipFuncSetAttribute(reinterpret_cast<const void*>(gemm_pipe<128>),
                      hipFuncAttributeMaxDynamicSharedMemorySize, 98304);

  cast_x_kernel<<<8192, 256, 0, stream>>>(x, xb);
  dim3 tb(32, 8);
  transpose_cast<<<dim3(64, 64), tb, 0, stream>>>(wq, wqkvT, 2048, 2048);
  transpose_cast<<<dim3(16, 64), tb, 0, stream>>>(wk, wqkvT + (size_t)2048 * 2048, 512, 2048);
  transpose_cast<<<dim3(16, 64), tb, 0, stream>>>(wv, wqkvT + (size_t)2560 * 2048, 512, 2048);
  transpose_cast<<<dim3(64, 64), tb, 0, stream>>>(wo, woT, 2048, 2048);

  gemm_pipe<256><<<192, 512, 131072, stream>>>(xb, wqkvT, qkv, 4096, NQKV, 0);
  rope_kernel<<<4096, 256, 0, stream>>>(qkv);
  vtrans_kernel<<<512, 256, 0, stream>>>(qkv, Vt);
  kvpack_kernel<<<1024, 64, 0, stream>>>(qkv, Vt, Kp, Vp);
  attn_kernel<<<2048, 128, 0, stream>>>(qkv, Kp, Vp, attnb);
  gemm_pipe<128><<<256, 512, 98304, stream>>>(attnb, woT, d_out, 4096, 2048, 1);
}

// Round 7
// 307.542 us; speedup vs baseline: 1.5764x; 1.5764x over previous
//
#include <hip/hip_runtime.h>

#define S_LEN 2048
#define NH 32
#define NKV 8
#define HEADD 64
#define DMODEL 2048
#define NQKV 3072

typedef float f32x4 __attribute__((ext_vector_type(4)));
typedef float f32x16 __attribute__((ext_vector_type(16)));
typedef short s16x8 __attribute__((ext_vector_type(8)));
typedef int   i32x4 __attribute__((ext_vector_type(4)));
typedef unsigned short u16;
typedef u16 u16x4 __attribute__((ext_vector_type(4)));

__device__ __forceinline__ float b2f(u16 u) {
  unsigned int x = ((unsigned int)u) << 16;
  float f;
  __builtin_memcpy(&f, &x, 4);
  return f;
}
__device__ __forceinline__ u16 f2b(float f) {
  unsigned int x;
  __builtin_memcpy(&x, &f, 4);
  unsigned int r = x + 0x7fffu + ((x >> 16) & 1u);
  return (u16)(r >> 16);
}
__device__ __forceinline__ unsigned fbits(float f) {
  unsigned x; __builtin_memcpy(&x, &f, 4); return x;
}

// async 16B/lane global -> LDS (LDS dest is wave-uniform base + lane*16)
__device__ __forceinline__ void gload_lds16(const u16* g, u16* l) {
  __builtin_amdgcn_global_load_lds((const __attribute__((address_space(1))) void*)g,
                                   (__attribute__((address_space(3))) void*)l, 16, 0, 0);
}

template<int N> __device__ __forceinline__ void wait_vm() {
  asm volatile("s_waitcnt vmcnt(%0)" :: "n"(N) : "memory");
}

// ---------- x fp32 -> bf16 ----------
__global__ void cast_x_kernel(const float* __restrict__ src, u16* __restrict__ dst) {
  int i = (blockIdx.x * 256 + threadIdx.x) * 4;
  f32x4 v = *(const f32x4*)(src + i);
  u16x4 o;
  o[0] = f2b(v[0]); o[1] = f2b(v[1]); o[2] = f2b(v[2]); o[3] = f2b(v[3]);
  *(u16x4*)(dst + i) = o;
}

// ---------- transpose + cast: src (K x N fp32) -> dst (N x K bf16) ----------
__global__ void transpose_cast(const float* __restrict__ src, u16* __restrict__ dst, int N, int K) {
  __shared__ float tile[32][33];
  int n0 = blockIdx.x * 32, k0 = blockIdx.y * 32;
  int tx = threadIdx.x, ty = threadIdx.y;  // (32, 8)
#pragma unroll
  for (int i = 0; i < 32; i += 8)
    tile[ty + i][tx] = src[(size_t)(k0 + ty + i) * N + n0 + tx];
  __syncthreads();
#pragma unroll
  for (int i = 0; i < 32; i += 8)
    dst[(size_t)(n0 + ty + i) * K + k0 + tx] = f2b(tile[tx][ty + i]);
}

// ---------- GEMM: 256-row tiles, 8 waves, 4-buffer counted-vmcnt pipeline ----------
// C(MxN) = A(MxK=2048) * Bt(NxK=2048)^T, bf16. BM=256, BN template (256 or 128).
// Per K32-step: wait vmcnt(2L) -> raw s_barrier -> stage step+3 -> ds_read -> 8xNF MFMA.
#define PIPE_BODY(Q, STAGE, VMN)                                                   \
  {                                                                                \
    wait_vm<VMN>();                                                                \
    __builtin_amdgcn_s_barrier();                                                  \
    __builtin_amdgcn_sched_barrier(0);                                             \
    if (STAGE) {                                                                   \
      u16* db = sm + ((Q + 3) & 3) * BUFE;                                         \
      gload_lds16(gA0, db + w * 1024);                                             \
      gload_lds16(gA1, db + w * 1024 + 512);                                       \
      if (BN == 256) {                                                             \
        gload_lds16(gB0, db + ABUF + w * 1024);                                    \
        gload_lds16(gB1, db + ABUF + w * 1024 + 512);                              \
      } else {                                                                     \
        gload_lds16(gB0, db + ABUF + w * 512);                                     \
      }                                                                            \
      gA0 += 32; gA1 += 32; gB0 += 32; if (BN == 256) gB1 += 32;                   \
    }                                                                              \
    const u16* bb = sm + Q * BUFE;                                                 \
    s16x8 af[8], bf[NF];                                                           \
    _Pragma("unroll") for (int i = 0; i < 8; i++)  af[i] = *(const s16x8*)(bb + aoff[i]); \
    _Pragma("unroll") for (int j = 0; j < NF; j++) bf[j] = *(const s16x8*)(bb + boff[j]); \
    __builtin_amdgcn_s_setprio(1);                                                 \
    _Pragma("unroll") for (int mi = 0; mi < 8; mi++)                               \
      _Pragma("unroll") for (int ni = 0; ni < NF; ni++)                            \
        acc[mi][ni] = __builtin_amdgcn_mfma_f32_16x16x32_bf16(af[mi], bf[ni], acc[mi][ni], 0, 0, 0); \
    __builtin_amdgcn_s_setprio(0);                                                 \
  }

template<int BN>
__global__ __launch_bounds__(512, 2) void gemm_pipe(
    const u16* __restrict__ A, const u16* __restrict__ Bt, void* __restrict__ Cout,
    int M, int N, int writeF32) {
  extern __shared__ __align__(16) u16 sm[];
  constexpr int NF   = BN / 64;        // n-frags per wave (4 or 2)
  constexpr int ABUF = 256 * 32;       // 8192 elems per buffer (A)
  constexpr int BUFE = ABUF + BN * 32; // elems per buffer (A+B)
  constexpr int LPS  = 2 + BN / 128;   // gloads per wave per step (4 or 3)

  int nb = N / BN;
  int nwg = (M >> 8) * nb;             // 192 or 256: both % 8 == 0
  int cpx = nwg >> 3;
  int bid = ((int)blockIdx.x & 7) * cpx + ((int)blockIdx.x >> 3);  // XCD swizzle
  int m0 = (bid / nb) << 8;
  int n0 = (bid % nb) * BN;

  int tid = threadIdx.x;
  int lane = tid & 63;
  int w = tid >> 6;                    // 0..7
  int wm8 = (w >> 2) << 7;             // 0 / 128
  int wn8 = (w & 3) * (BN / 4);
  int l15 = lane & 15;
  int quad = lane >> 4;

  // staging source addresses (pre-swizzled global, linear LDS dest)
  int lr = lane >> 3;
  int lc = lane & 7;
  int slot = lc ^ lr;
  int kc8 = (slot & 3) << 3;
  const u16* gA0 = A + (size_t)(m0 + w * 32 + (lr << 1) + (slot >> 2)) * 2048 + kc8;
  const u16* gA1 = gA0 + (size_t)16 * 2048;
  const u16* gB0;
  const u16* gB1;
  if (BN == 256) {
    gB0 = Bt + (size_t)(n0 + w * 32 + (lr << 1) + (slot >> 2)) * 2048 + kc8;
    gB1 = gB0 + (size_t)16 * 2048;
  } else {
    gB0 = Bt + (size_t)(n0 + w * 16 + (lr << 1) + (slot >> 2)) * 2048 + kc8;
    gB1 = gB0;
  }

  // fragment ds_read offsets (elements), swizzled
  int rb = l15 >> 1;
  int sl = (((((l15 & 1) << 2) | quad) ^ rb)) << 3;
  int rbase = rb * 64 + sl;
  int aoff[8], boff[NF];
#pragma unroll
  for (int i = 0; i < 8; i++) aoff[i] = wm8 * 32 + i * 512 + rbase;
#pragma unroll
  for (int j = 0; j < NF; j++) boff[j] = ABUF + wn8 * 32 + j * 512 + rbase;

  f32x4 acc[8][NF] = {};

  // prologue: stage steps 0,1,2 into bufs 0,1,2
#pragma unroll
  for (int pt = 0; pt < 3; pt++) {
    u16* db = sm + pt * BUFE;
    gload_lds16(gA0, db + w * 1024);
    gload_lds16(gA1, db + w * 1024 + 512);
    if (BN == 256) {
      gload_lds16(gB0, db + ABUF + w * 1024);
      gload_lds16(gB1, db + ABUF + w * 1024 + 512);
    } else {
      gload_lds16(gB0, db + ABUF + w * 512);
    }
    gA0 += 32; gA1 += 32; gB0 += 32; if (BN == 256) gB1 += 32;
  }

#pragma unroll 1
  for (int it = 0; it < 15; ++it) {
    PIPE_BODY(0, 1, 2 * LPS)
    PIPE_BODY(1, 1, 2 * LPS)
    PIPE_BODY(2, 1, 2 * LPS)
    PIPE_BODY(3, 1, 2 * LPS)
  }
  PIPE_BODY(0, 1, 2 * LPS)
  PIPE_BODY(1, 0, 2 * LPS)
  PIPE_BODY(2, 0, LPS)
  PIPE_BODY(3, 0, 0)

#pragma unroll
  for (int mi = 0; mi < 8; mi++)
#pragma unroll
    for (int ni = 0; ni < NF; ni++)
#pragma unroll
      for (int r = 0; r < 4; r++) {
        int row = m0 + wm8 + mi * 16 + (quad << 2) + r;
        int col = n0 + wn8 + ni * 16 + l15;
        float v = acc[mi][ni][r];
        if (writeF32) ((float*)Cout)[(size_t)row * N + col] = v;
        else ((u16*)Cout)[(size_t)row * N + col] = f2b(v);
      }
}

// ---------- in-place RoPE on q (scaled by 0.125*log2e -> base-2 softmax domain) and k ----------
__global__ void rope_kernel(u16* __restrict__ qkv) {
  int row = blockIdx.x;
  int s = row & (S_LEN - 1);
  u16* p = qkv + (size_t)row * NQKV;
  int t = threadIdx.x;
  int d = t & 31;
  int hh = t >> 5;
  float inv_freq = exp2f(-(float)d * (13.287712379549449f / 32.0f));
  float ang = (float)s * inv_freq;
  float sn, cs;
  sincosf(ang, &sn, &cs);
  const float QSCALE = 0.18033688011112042f;  // 0.125 * log2(e)
#pragma unroll
  for (int i = 0; i < 4; i++) {
    int base = (hh + (i << 3)) * HEADD + d;
    float x1 = b2f(p[base]);
    float x2 = b2f(p[base + 32]);
    p[base]      = f2b((x1 * cs - x2 * sn) * QSCALE);
    p[base + 32] = f2b((x1 * sn + x2 * cs) * QSCALE);
  }
  {
    int base = DMODEL + hh * HEADD + d;
    float x1 = b2f(p[base]);
    float x2 = b2f(p[base + 32]);
    p[base]      = f2b(x1 * cs - x2 * sn);
    p[base + 32] = f2b(x1 * sn + x2 * cs);
  }
}

// ---------- V transpose: qkv v-slice -> Vt[b][g][d=64][s=2048] ----------
__global__ void vtrans_kernel(const u16* __restrict__ qkv, u16* __restrict__ Vt) {
  __shared__ __align__(16) u16 tile[64][72];
  int bid = blockIdx.x;  // 2*8*32 = 512
  int st = bid & 31;
  int g  = (bid >> 5) & 7;
  int b  = bid >> 8;
  int tid = threadIdx.x;
  int r = tid >> 2;
  int c = (tid & 3) << 4;
  const u16* src = qkv + (size_t)(b * S_LEN + st * 64 + r) * NQKV + 2560 + g * 64 + c;
  *(i32x4*)&tile[r][c]     = *(const i32x4*)src;
  *(i32x4*)&tile[r][c + 8] = *(const i32x4*)(src + 8);
  __syncthreads();
  u16* dst = Vt + (size_t)((b * 8 + g) * 64 + r) * S_LEN + st * 64 + c;
  u16 tmp[16];
#pragma unroll
  for (int j = 0; j < 16; j++) tmp[j] = tile[c + j][r];
  *(i32x4*)dst       = *(i32x4*)&tmp[0];
  *(i32x4*)(dst + 8) = *(i32x4*)&tmp[8];
}

// ---------- pack K & V into fragment-ordered tiles ----------
__global__ __launch_bounds__(64) void kvpack_kernel(const u16* __restrict__ qkv,
                                                    const u16* __restrict__ Vt,
                                                    u16* __restrict__ Kp,
                                                    u16* __restrict__ Vp) {
  int bid = blockIdx.x;  // 1024 = bg*64 + kb
  int kb = bid & 63;
  int bg = bid >> 6;
  int g = bg & 7;
  int b = bg >> 3;
  int lane = threadIdx.x;
  int l31 = lane & 31;
  int h2 = lane >> 5;

  const u16* kq = qkv + (size_t)(b * S_LEN + kb * 32 + l31) * NQKV + DMODEL + g * 64 + h2 * 8;
  u16* kdst = Kp + ((size_t)bid * 4) * 512 + lane * 8;
#pragma unroll
  for (int t = 0; t < 4; t++)
    *(i32x4*)(kdst + t * 512) = *(const i32x4*)(kq + t * 16);

  const u16* vq = Vt + (size_t)(bg * 64 + l31) * S_LEN + kb * 32 + h2 * 8;
  u16* vdst = Vp + ((size_t)bid * 4) * 512 + lane * 8;
  *(i32x4*)(vdst)        = *(const i32x4*)vq;
  *(i32x4*)(vdst + 512)  = *(const i32x4*)(vq + 16);
  *(i32x4*)(vdst + 1024) = *(const i32x4*)(vq + (size_t)32 * S_LEN);
  *(i32x4*)(vdst + 1536) = *(const i32x4*)(vq + (size_t)32 * S_LEN + 16);
}

// ---------- MFMA flash attention: pair-balanced, 4-wave k-split ----------
// Block (of 2048) owns qb-pair (63-pr, pr) = 65 tiles. Per pass, all FOUR waves
// split that pass's k-range (softmax additive without online-max); partials
// combined through LDS. Every wave ~16 tiles -> uniform work, sustained
// multi-wave residency, no drain tail. NO min-occupancy launch bound (r6: forcing
// it crushed VGPR to 64 and spilled 690MB to scratch).
__global__ __launch_bounds__(256) void attn_kernel(const u16* __restrict__ qkv,
                                                   const u16* __restrict__ Kp,
                                                   const u16* __restrict__ Vp,
                                                   u16* __restrict__ out) {
  __shared__ float red[3 * 33 * 64];  // waves 1..3 partials: 32 acc + 1 l per lane

  int bid = blockIdx.x;      // 2048 = pr(32) * 64
  int bh = bid & 63;
  int pr = bid >> 6;         // 0..31
  int h = bh & 31;
  int b = bh >> 5;
  int g = h >> 2;
  int bg = b * 8 + g;
  int tid = threadIdx.x;
  int wv = tid >> 6;         // 0..3
  int lane = tid & 63;
  int l31 = lane & 31;
  int h2 = lane >> 5;

  const u16* kp = Kp + ((size_t)bg * 64) * 2048 + lane * 8;
  const u16* vp = Vp + ((size_t)bg * 64) * 2048 + lane * 8;

#pragma unroll 1
  for (int pass = 0; pass < 2; ++pass) {
    int qb = pass ? pr : (63 - pr);
    int q0 = qb << 5;
    int nt = qb + 1;
    int k_lo = (nt * wv) >> 2;
    int k_hi = (nt * (wv + 1)) >> 2;

    const u16* qp = qkv + (size_t)(b * S_LEN + q0 + l31) * NQKV + h * HEADD + h2 * 8;
    s16x8 qf[4];
#pragma unroll
    for (int t = 0; t < 4; t++) qf[t] = *(const s16x8*)(qp + t * 16);

    float l_i = 0.f;
    f32x16 acc[2] = {};

    s16x8 kfa[4], vfa[4], kfb[4], vfb[4];

    auto loadkv = [&](int kb, s16x8 (&kf)[4], s16x8 (&vf)[4]) {
      const u16* kpp = kp + (size_t)kb * 2048;
      const u16* vpp = vp + (size_t)kb * 2048;
#pragma unroll
      for (int t = 0; t < 4; t++) {
        kf[t] = *(const s16x8*)(kpp + t * 512);
        vf[t] = *(const s16x8*)(vpp + t * 512);
      }
    };

    auto compute = [&](int kb, s16x8 (&kf)[4], s16x8 (&vf)[4]) {
      f32x16 sc = {};
      __builtin_amdgcn_s_setprio(1);
#pragma unroll
      for (int t = 0; t < 4; t++)
        sc = __builtin_amdgcn_mfma_f32_32x32x16_bf16(kf[t], qf[t], sc, 0, 0, 0);
      __builtin_amdgcn_s_setprio(0);

      float sv[16];
#pragma unroll
      for (int j = 0; j < 16; j++) sv[j] = sc[j];

      if (kb == qb) {
        int qg = q0 + l31;
#pragma unroll
        for (int j = 0; j < 16; j++) {
          int kg = kb * 32 + (j & 3) + ((j >> 2) << 3) + (h2 << 2);
          if (kg > qg) sv[j] = -1e30f;
        }
      }

      float e[16];
#pragma unroll
      for (int j = 0; j < 16; j++) e[j] = __builtin_amdgcn_exp2f(sv[j]);

      float ps = (((e[0] + e[1]) + (e[2] + e[3])) + ((e[4] + e[5]) + (e[6] + e[7])))
               + (((e[8] + e[9]) + (e[10] + e[11])) + ((e[12] + e[13]) + (e[14] + e[15])));
      ps += __shfl_xor(ps, 32);
      l_i += ps;

      unsigned Pk[8], Ex[8];
#pragma unroll
      for (int r = 0; r < 8; r++) {
        unsigned pk;
        asm("v_cvt_pk_bf16_f32 %0, %1, %2" : "=v"(pk) : "v"(e[2 * r]), "v"(e[2 * r + 1]));
        Pk[r] = pk;
      }
#pragma unroll
      for (int r = 0; r < 8; r++) Ex[r] = (unsigned)__shfl_xor((int)Pk[r], 32);

      unsigned B0u[4], B1u[4];
      B0u[0] = h2 ? Ex[2] : Pk[0];
      B0u[1] = h2 ? Ex[3] : Pk[1];
      B0u[2] = h2 ? Pk[2] : Ex[0];
      B0u[3] = h2 ? Pk[3] : Ex[1];
      B1u[0] = h2 ? Ex[6] : Pk[4];
      B1u[1] = h2 ? Ex[7] : Pk[5];
      B1u[2] = h2 ? Pk[6] : Ex[4];
      B1u[3] = h2 ? Pk[7] : Ex[5];
      s16x8 B0, B1;
      __builtin_memcpy(&B0, B0u, 16);
      __builtin_memcpy(&B1, B1u, 16);

      __builtin_amdgcn_s_setprio(1);
      acc[0] = __builtin_amdgcn_mfma_f32_32x32x16_bf16(vf[0], B0, acc[0], 0, 0, 0);
      acc[0] = __builtin_amdgcn_mfma_f32_32x32x16_bf16(vf[1], B1, acc[0], 0, 0, 0);
      acc[1] = __builtin_amdgcn_mfma_f32_32x32x16_bf16(vf[2], B0, acc[1], 0, 0, 0);
      acc[1] = __builtin_amdgcn_mfma_f32_32x32x16_bf16(vf[3], B1, acc[1], 0, 0, 0);
      __builtin_amdgcn_s_setprio(0);
    };

    if (k_lo < k_hi) {
      loadkv(k_lo, kfa, vfa);
      int kb = k_lo;
      while (true) {
        if (kb + 1 < k_hi) loadkv(kb + 1, kfb, vfb);
        compute(kb, kfa, vfa);
        if (++kb >= k_hi) break;
        if (kb + 1 < k_hi) loadkv(kb + 1, kfa, vfa);
        compute(kb, kfb, vfb);
        if (++kb >= k_hi) break;
      }
    }

    // combine the four waves' partial (acc, l) through LDS
    __syncthreads();   // wave0 done reading red[] of the previous pass
    if (wv) {
      float* rp = red + (wv - 1) * 2112;
#pragma unroll
      for (int dt = 0; dt < 2; dt++)
#pragma unroll
        for (int j = 0; j < 16; j++) rp[(dt * 16 + j) * 64 + lane] = acc[dt][j];
      rp[32 * 64 + lane] = l_i;
    }
    __syncthreads();
    if (!wv) {
#pragma unroll
      for (int p = 0; p < 3; p++) {
        const float* rp = red + p * 2112;
#pragma unroll
        for (int dt = 0; dt < 2; dt++)
#pragma unroll
          for (int j = 0; j < 16; j++) acc[dt][j] += rp[(dt * 16 + j) * 64 + lane];
        l_i += rp[32 * 64 + lane];
      }
      float linv = 1.0f / l_i;
      u16* op = out + (size_t)(b * S_LEN + q0 + l31) * DMODEL + h * HEADD;
#pragma unroll
      for (int dt = 0; dt < 2; dt++)
#pragma unroll
        for (int rg = 0; rg < 4; rg++) {
          u16x4 t4;
#pragma unroll
          for (int j = 0; j < 4; j++) t4[j] = f2b(acc[dt][rg * 4 + j] * linv);
          *(u16x4*)(op + dt * 32 + rg * 8 + h2 * 4) = t4;
        }
    }
  }
}

extern "C" void kernel_launch(void* const* d_in, const int* in_sizes, int n_in,
                              void* d_out, int out_size, void* d_ws, size_t ws_size,
                              hipStream_t stream) {
  const float* x  = (const float*)d_in[0];
  const float* wq = (const float*)d_in[1];
  const float* wk = (const float*)d_in[2];
  const float* wv = (const float*)d_in[3];
  const float* wo = (const float*)d_in[4];

  char* ws = (char*)d_ws;
  u16* xb    = (u16*)ws;                                   // 4096x2048 bf16 (16.8 MB)
  u16* wqkvT = (u16*)(ws + 16777216);                      // 3072x2048 (12.6 MB)
  u16* woT   = (u16*)(ws + 16777216 + 12582912);           // 2048x2048 (8.4 MB)
  u16* qkv   = (u16*)(ws + 16777216 + 12582912 + 8388608); // 4096x3072 (25.2 MB)
  u16* attnb = xb;                                  // xb dead after gemm1
  u16* Vt    = wqkvT;                               // wqkvT region reused after gemm1
  u16* Kp    = (u16*)(ws + 16777216 + 4194304);
  u16* Vp    = (u16*)(ws + 16777216 + 8388608);

  // allow >64KB dynamic LDS for the pipelined GEMMs
  hipFuncSetAttribute(reinterpret_cast<const void*>(gemm_pipe<256>),
                      hipFuncAttributeMaxDynamicSharedMemorySize, 131072);
  hipFuncSetAttribute(reinterpret_cast<const void*>(gemm_pipe<128>),
                      hipFuncAttributeMaxDynamicSharedMemorySize, 98304);

  cast_x_kernel<<<8192, 256, 0, stream>>>(x, xb);
  dim3 tb(32, 8);
  transpose_cast<<<dim3(64, 64), tb, 0, stream>>>(wq, wqkvT, 2048, 2048);
  transpose_cast<<<dim3(16, 64), tb, 0, stream>>>(wk, wqkvT + (size_t)2048 * 2048, 512, 2048);
  transpose_cast<<<dim3(16, 64), tb, 0, stream>>>(wv, wqkvT + (size_t)2560 * 2048, 512, 2048);
  transpose_cast<<<dim3(64, 64), tb, 0, stream>>>(wo, woT, 2048, 2048);

  gemm_pipe<256><<<192, 512, 131072, stream>>>(xb, wqkvT, qkv, 4096, NQKV, 0);
  rope_kernel<<<4096, 256, 0, stream>>>(qkv);
  vtrans_kernel<<<512, 256, 0, stream>>>(qkv, Vt);
  kvpack_kernel<<<1024, 64, 0, stream>>>(qkv, Vt, Kp, Vp);
  attn_kernel<<<2048, 256, 0, stream>>>(qkv, Kp, Vp, attnb);
  gemm_pipe<128><<<256, 512, 98304, stream>>>(attnb, woT, d_out, 4096, 2048, 1);
}

// Round 8
// 285.882 us; speedup vs baseline: 1.6958x; 1.0758x over previous
//
#include <hip/hip_runtime.h>

#define S_LEN 2048
#define NH 32
#define NKV 8
#define HEADD 64
#define DMODEL 2048
#define NQKV 3072

typedef float f32x4 __attribute__((ext_vector_type(4)));
typedef float f32x16 __attribute__((ext_vector_type(16)));
typedef short s16x8 __attribute__((ext_vector_type(8)));
typedef int   i32x4 __attribute__((ext_vector_type(4)));
typedef unsigned short u16;
typedef u16 u16x4 __attribute__((ext_vector_type(4)));

__device__ __forceinline__ float b2f(u16 u) {
  unsigned int x = ((unsigned int)u) << 16;
  float f;
  __builtin_memcpy(&f, &x, 4);
  return f;
}
__device__ __forceinline__ u16 f2b(float f) {
  unsigned int x;
  __builtin_memcpy(&x, &f, 4);
  unsigned int r = x + 0x7fffu + ((x >> 16) & 1u);
  return (u16)(r >> 16);
}
__device__ __forceinline__ unsigned fbits(float f) {
  unsigned x; __builtin_memcpy(&x, &f, 4); return x;
}

// async 16B/lane global -> LDS (LDS dest is wave-uniform base + lane*16)
__device__ __forceinline__ void gload_lds16(const u16* g, u16* l) {
  __builtin_amdgcn_global_load_lds((const __attribute__((address_space(1))) void*)g,
                                   (__attribute__((address_space(3))) void*)l, 16, 0, 0);
}

template<int N> __device__ __forceinline__ void wait_vm() {
  asm volatile("s_waitcnt vmcnt(%0)" :: "n"(N) : "memory");
}

// ---------- x fp32 -> bf16 ----------
__global__ void cast_x_kernel(const float* __restrict__ src, u16* __restrict__ dst) {
  int i = (blockIdx.x * 256 + threadIdx.x) * 4;
  f32x4 v = *(const f32x4*)(src + i);
  u16x4 o;
  o[0] = f2b(v[0]); o[1] = f2b(v[1]); o[2] = f2b(v[2]); o[3] = f2b(v[3]);
  *(u16x4*)(dst + i) = o;
}

// ---------- transpose + cast: src (K x N fp32) -> dst (N x K bf16) ----------
__global__ void transpose_cast(const float* __restrict__ src, u16* __restrict__ dst, int N, int K) {
  __shared__ float tile[32][33];
  int n0 = blockIdx.x * 32, k0 = blockIdx.y * 32;
  int tx = threadIdx.x, ty = threadIdx.y;  // (32, 8)
#pragma unroll
  for (int i = 0; i < 32; i += 8)
    tile[ty + i][tx] = src[(size_t)(k0 + ty + i) * N + n0 + tx];
  __syncthreads();
#pragma unroll
  for (int i = 0; i < 32; i += 8)
    dst[(size_t)(n0 + ty + i) * K + k0 + tx] = f2b(tile[tx][ty + i]);
}

// ---------- GEMM: 256-row tiles, 8 waves, 4-buffer counted-vmcnt pipeline ----------
// C(MxN) = A(MxK=2048) * Bt(NxK=2048)^T, bf16. BM=256, BN template (256 or 128).
// Per K32-step: wait vmcnt(2L) -> raw s_barrier -> stage step+3 -> ds_read -> 8xNF MFMA.
#define PIPE_BODY(Q, STAGE, VMN)                                                   \
  {                                                                                \
    wait_vm<VMN>();                                                                \
    __builtin_amdgcn_s_barrier();                                                  \
    __builtin_amdgcn_sched_barrier(0);                                             \
    if (STAGE) {                                                                   \
      u16* db = sm + ((Q + 3) & 3) * BUFE;                                         \
      gload_lds16(gA0, db + w * 1024);                                             \
      gload_lds16(gA1, db + w * 1024 + 512);                                       \
      if (BN == 256) {                                                             \
        gload_lds16(gB0, db + ABUF + w * 1024);                                    \
        gload_lds16(gB1, db + ABUF + w * 1024 + 512);                              \
      } else {                                                                     \
        gload_lds16(gB0, db + ABUF + w * 512);                                     \
      }                                                                            \
      gA0 += 32; gA1 += 32; gB0 += 32; if (BN == 256) gB1 += 32;                   \
    }                                                                              \
    const u16* bb = sm + Q * BUFE;                                                 \
    s16x8 af[8], bf[NF];                                                           \
    _Pragma("unroll") for (int i = 0; i < 8; i++)  af[i] = *(const s16x8*)(bb + aoff[i]); \
    _Pragma("unroll") for (int j = 0; j < NF; j++) bf[j] = *(const s16x8*)(bb + boff[j]); \
    __builtin_amdgcn_s_setprio(1);                                                 \
    _Pragma("unroll") for (int mi = 0; mi < 8; mi++)                               \
      _Pragma("unroll") for (int ni = 0; ni < NF; ni++)                            \
        acc[mi][ni] = __builtin_amdgcn_mfma_f32_16x16x32_bf16(af[mi], bf[ni], acc[mi][ni], 0, 0, 0); \
    __builtin_amdgcn_s_setprio(0);                                                 \
  }

template<int BN>
__global__ __launch_bounds__(512, 2) void gemm_pipe(
    const u16* __restrict__ A, const u16* __restrict__ Bt, void* __restrict__ Cout,
    int M, int N, int writeF32) {
  extern __shared__ __align__(16) u16 sm[];
  constexpr int NF   = BN / 64;        // n-frags per wave (4 or 2)
  constexpr int ABUF = 256 * 32;       // 8192 elems per buffer (A)
  constexpr int BUFE = ABUF + BN * 32; // elems per buffer (A+B)
  constexpr int LPS  = 2 + BN / 128;   // gloads per wave per step (4 or 3)

  int nb = N / BN;
  int nwg = (M >> 8) * nb;             // 192 or 256: both % 8 == 0
  int cpx = nwg >> 3;
  int bid = ((int)blockIdx.x & 7) * cpx + ((int)blockIdx.x >> 3);  // XCD swizzle
  int m0 = (bid / nb) << 8;
  int n0 = (bid % nb) * BN;

  int tid = threadIdx.x;
  int lane = tid & 63;
  int w = tid >> 6;                    // 0..7
  int wm8 = (w >> 2) << 7;             // 0 / 128
  int wn8 = (w & 3) * (BN / 4);
  int l15 = lane & 15;
  int quad = lane >> 4;

  // staging source addresses (pre-swizzled global, linear LDS dest)
  int lr = lane >> 3;
  int lc = lane & 7;
  int slot = lc ^ lr;
  int kc8 = (slot & 3) << 3;
  const u16* gA0 = A + (size_t)(m0 + w * 32 + (lr << 1) + (slot >> 2)) * 2048 + kc8;
  const u16* gA1 = gA0 + (size_t)16 * 2048;
  const u16* gB0;
  const u16* gB1;
  if (BN == 256) {
    gB0 = Bt + (size_t)(n0 + w * 32 + (lr << 1) + (slot >> 2)) * 2048 + kc8;
    gB1 = gB0 + (size_t)16 * 2048;
  } else {
    gB0 = Bt + (size_t)(n0 + w * 16 + (lr << 1) + (slot >> 2)) * 2048 + kc8;
    gB1 = gB0;
  }

  // fragment ds_read offsets (elements), swizzled
  int rb = l15 >> 1;
  int sl = (((((l15 & 1) << 2) | quad) ^ rb)) << 3;
  int rbase = rb * 64 + sl;
  int aoff[8], boff[NF];
#pragma unroll
  for (int i = 0; i < 8; i++) aoff[i] = wm8 * 32 + i * 512 + rbase;
#pragma unroll
  for (int j = 0; j < NF; j++) boff[j] = ABUF + wn8 * 32 + j * 512 + rbase;

  f32x4 acc[8][NF] = {};

  // prologue: stage steps 0,1,2 into bufs 0,1,2
#pragma unroll
  for (int pt = 0; pt < 3; pt++) {
    u16* db = sm + pt * BUFE;
    gload_lds16(gA0, db + w * 1024);
    gload_lds16(gA1, db + w * 1024 + 512);
    if (BN == 256) {
      gload_lds16(gB0, db + ABUF + w * 1024);
      gload_lds16(gB1, db + ABUF + w * 1024 + 512);
    } else {
      gload_lds16(gB0, db + ABUF + w * 512);
    }
    gA0 += 32; gA1 += 32; gB0 += 32; if (BN == 256) gB1 += 32;
  }

#pragma unroll 1
  for (int it = 0; it < 15; ++it) {
    PIPE_BODY(0, 1, 2 * LPS)
    PIPE_BODY(1, 1, 2 * LPS)
    PIPE_BODY(2, 1, 2 * LPS)
    PIPE_BODY(3, 1, 2 * LPS)
  }
  PIPE_BODY(0, 1, 2 * LPS)
  PIPE_BODY(1, 0, 2 * LPS)
  PIPE_BODY(2, 0, LPS)
  PIPE_BODY(3, 0, 0)

#pragma unroll
  for (int mi = 0; mi < 8; mi++)
#pragma unroll
    for (int ni = 0; ni < NF; ni++)
#pragma unroll
      for (int r = 0; r < 4; r++) {
        int row = m0 + wm8 + mi * 16 + (quad << 2) + r;
        int col = n0 + wn8 + ni * 16 + l15;
        float v = acc[mi][ni][r];
        if (writeF32) ((float*)Cout)[(size_t)row * N + col] = v;
        else ((u16*)Cout)[(size_t)row * N + col] = f2b(v);
      }
}

// ---------- in-place RoPE on q (scaled by 0.125*log2e -> base-2 softmax domain) and k ----------
// sincos dedup: a block has only 32 unique (s,d) angles (d = t&31); lanes 0-31
// compute them once into LDS, the other 224 threads just read. Cuts libm
// transcendental work 8x.
__global__ void rope_kernel(u16* __restrict__ qkv) {
  __shared__ float cs_s[32], sn_s[32];
  int row = blockIdx.x;
  int s = row & (S_LEN - 1);
  u16* p = qkv + (size_t)row * NQKV;
  int t = threadIdx.x;
  int d = t & 31;
  int hh = t >> 5;
  if (t < 32) {
    float inv_freq = exp2f(-(float)t * (13.287712379549449f / 32.0f));
    float ang = (float)s * inv_freq;
    float sn, cs;
    sincosf(ang, &sn, &cs);
    cs_s[t] = cs;
    sn_s[t] = sn;
  }
  __syncthreads();
  float cs = cs_s[d], sn = sn_s[d];
  const float QSCALE = 0.18033688011112042f;  // 0.125 * log2(e)
#pragma unroll
  for (int i = 0; i < 4; i++) {
    int base = (hh + (i << 3)) * HEADD + d;
    float x1 = b2f(p[base]);
    float x2 = b2f(p[base + 32]);
    p[base]      = f2b((x1 * cs - x2 * sn) * QSCALE);
    p[base + 32] = f2b((x1 * sn + x2 * cs) * QSCALE);
  }
  {
    int base = DMODEL + hh * HEADD + d;
    float x1 = b2f(p[base]);
    float x2 = b2f(p[base + 32]);
    p[base]      = f2b(x1 * cs - x2 * sn);
    p[base + 32] = f2b(x1 * sn + x2 * cs);
  }
}

// ---------- V transpose: qkv v-slice -> Vt[b][g][d=64][s=2048] ----------
__global__ void vtrans_kernel(const u16* __restrict__ qkv, u16* __restrict__ Vt) {
  __shared__ __align__(16) u16 tile[64][72];
  int bid = blockIdx.x;  // 2*8*32 = 512
  int st = bid & 31;
  int g  = (bid >> 5) & 7;
  int b  = bid >> 8;
  int tid = threadIdx.x;
  int r = tid >> 2;
  int c = (tid & 3) << 4;
  const u16* src = qkv + (size_t)(b * S_LEN + st * 64 + r) * NQKV + 2560 + g * 64 + c;
  *(i32x4*)&tile[r][c]     = *(const i32x4*)src;
  *(i32x4*)&tile[r][c + 8] = *(const i32x4*)(src + 8);
  __syncthreads();
  u16* dst = Vt + (size_t)((b * 8 + g) * 64 + r) * S_LEN + st * 64 + c;
  u16 tmp[16];
#pragma unroll
  for (int j = 0; j < 16; j++) tmp[j] = tile[c + j][r];
  *(i32x4*)dst       = *(i32x4*)&tmp[0];
  *(i32x4*)(dst + 8) = *(i32x4*)&tmp[8];
}

// ---------- pack K & V into fragment-ordered tiles ----------
__global__ __launch_bounds__(64) void kvpack_kernel(const u16* __restrict__ qkv,
                                                    const u16* __restrict__ Vt,
                                                    u16* __restrict__ Kp,
                                                    u16* __restrict__ Vp) {
  int bid = blockIdx.x;  // 1024 = bg*64 + kb
  int kb = bid & 63;
  int bg = bid >> 6;
  int g = bg & 7;
  int b = bg >> 3;
  int lane = threadIdx.x;
  int l31 = lane & 31;
  int h2 = lane >> 5;

  const u16* kq = qkv + (size_t)(b * S_LEN + kb * 32 + l31) * NQKV + DMODEL + g * 64 + h2 * 8;
  u16* kdst = Kp + ((size_t)bid * 4) * 512 + lane * 8;
#pragma unroll
  for (int t = 0; t < 4; t++)
    *(i32x4*)(kdst + t * 512) = *(const i32x4*)(kq + t * 16);

  const u16* vq = Vt + (size_t)(bg * 64 + l31) * S_LEN + kb * 32 + h2 * 8;
  u16* vdst = Vp + ((size_t)bid * 4) * 512 + lane * 8;
  *(i32x4*)(vdst)        = *(const i32x4*)vq;
  *(i32x4*)(vdst + 512)  = *(const i32x4*)(vq + 16);
  *(i32x4*)(vdst + 1024) = *(const i32x4*)(vq + (size_t)32 * S_LEN);
  *(i32x4*)(vdst + 1536) = *(const i32x4*)(vq + (size_t)32 * S_LEN + 16);
}

// ---------- MFMA flash attention (r3 structure: 4096x1-wave, measured 66.6us) ----------
// Longest blocks launch first; no online-max (base-2 log domain scores, bounded);
// cvt_pk bf16 pack (fewer VALU than perm path, same layout).
__global__ __launch_bounds__(64) void attn_kernel(const u16* __restrict__ qkv,
                                                  const u16* __restrict__ Kp,
                                                  const u16* __restrict__ Vp,
                                                  u16* __restrict__ out) {
  int bid = blockIdx.x;
  int bh = bid & 63;
  int qb = 63 - (bid >> 6);  // longest blocks launch first
  int h = bh & 31;
  int b = bh >> 5;
  int g = h >> 2;
  int bg = b * 8 + g;
  int lane = threadIdx.x;
  int l31 = lane & 31;
  int h2 = lane >> 5;
  int q0 = qb << 5;

  const u16* qp = qkv + (size_t)(b * S_LEN + q0 + l31) * NQKV + h * HEADD + h2 * 8;
  s16x8 qf[4];
#pragma unroll
  for (int t = 0; t < 4; t++) qf[t] = *(const s16x8*)(qp + t * 16);

  const u16* kp = Kp + ((size_t)bg * 64) * 2048 + lane * 8;
  const u16* vp = Vp + ((size_t)bg * 64) * 2048 + lane * 8;

  float l_i = 0.f;
  f32x16 acc[2] = {};

  s16x8 kfa[4], vfa[4], kfb[4], vfb[4];

  auto loadkv = [&](int kb, s16x8 (&kf)[4], s16x8 (&vf)[4]) {
    const u16* kpp = kp + (size_t)kb * 2048;
    const u16* vpp = vp + (size_t)kb * 2048;
#pragma unroll
    for (int t = 0; t < 4; t++) {
      kf[t] = *(const s16x8*)(kpp + t * 512);
      vf[t] = *(const s16x8*)(vpp + t * 512);
    }
  };

  auto compute = [&](int kb, s16x8 (&kf)[4], s16x8 (&vf)[4]) {
    f32x16 sc = {};
    __builtin_amdgcn_s_setprio(1);
#pragma unroll
    for (int t = 0; t < 4; t++)
      sc = __builtin_amdgcn_mfma_f32_32x32x16_bf16(kf[t], qf[t], sc, 0, 0, 0);
    __builtin_amdgcn_s_setprio(0);

    float sv[16];
#pragma unroll
    for (int j = 0; j < 16; j++) sv[j] = sc[j];

    if (kb == qb) {
      int qg = q0 + l31;
#pragma unroll
      for (int j = 0; j < 16; j++) {
        int kg = kb * 32 + (j & 3) + ((j >> 2) << 3) + (h2 << 2);
        if (kg > qg) sv[j] = -1e30f;
      }
    }

    float e[16];
#pragma unroll
    for (int j = 0; j < 16; j++) e[j] = __builtin_amdgcn_exp2f(sv[j]);

    float ps = (((e[0] + e[1]) + (e[2] + e[3])) + ((e[4] + e[5]) + (e[6] + e[7])))
             + (((e[8] + e[9]) + (e[10] + e[11])) + ((e[12] + e[13]) + (e[14] + e[15])));
    ps += __shfl_xor(ps, 32);
    l_i += ps;

    // bf16 pack: one v_cvt_pk_bf16_f32 per pair (lo=even, hi=odd), RNE.
    unsigned Pk[8], Ex[8];
#pragma unroll
    for (int r = 0; r < 8; r++) {
      unsigned pk;
      asm("v_cvt_pk_bf16_f32 %0, %1, %2" : "=v"(pk) : "v"(e[2 * r]), "v"(e[2 * r + 1]));
      Pk[r] = pk;
    }
#pragma unroll
    for (int r = 0; r < 8; r++) Ex[r] = (unsigned)__shfl_xor((int)Pk[r], 32);

    unsigned B0u[4], B1u[4];
    B0u[0] = h2 ? Ex[2] : Pk[0];
    B0u[1] = h2 ? Ex[3] : Pk[1];
    B0u[2] = h2 ? Pk[2] : Ex[0];
    B0u[3] = h2 ? Pk[3] : Ex[1];
    B1u[0] = h2 ? Ex[6] : Pk[4];
    B1u[1] = h2 ? Ex[7] : Pk[5];
    B1u[2] = h2 ? Pk[6] : Ex[4];
    B1u[3] = h2 ? Pk[7] : Ex[5];
    s16x8 B0, B1;
    __builtin_memcpy(&B0, B0u, 16);
    __builtin_memcpy(&B1, B1u, 16);

    __builtin_amdgcn_s_setprio(1);
    acc[0] = __builtin_amdgcn_mfma_f32_32x32x16_bf16(vf[0], B0, acc[0], 0, 0, 0);
    acc[0] = __builtin_amdgcn_mfma_f32_32x32x16_bf16(vf[1], B1, acc[0], 0, 0, 0);
    acc[1] = __builtin_amdgcn_mfma_f32_32x32x16_bf16(vf[2], B0, acc[1], 0, 0, 0);
    acc[1] = __builtin_amdgcn_mfma_f32_32x32x16_bf16(vf[3], B1, acc[1], 0, 0, 0);
    __builtin_amdgcn_s_setprio(0);
  };

  loadkv(0, kfa, vfa);
  int kb = 0;
  while (true) {
    if (kb < qb) loadkv(kb + 1, kfb, vfb);
    compute(kb, kfa, vfa);
    if (++kb > qb) break;
    if (kb < qb) loadkv(kb + 1, kfa, vfa);
    compute(kb, kfb, vfb);
    if (++kb > qb) break;
  }

  float linv = 1.0f / l_i;
  u16* op = out + (size_t)(b * S_LEN + q0 + l31) * DMODEL + h * HEADD;
#pragma unroll
  for (int dt = 0; dt < 2; dt++)
#pragma unroll
    for (int rg = 0; rg < 4; rg++) {
      u16x4 t4;
#pragma unroll
      for (int j = 0; j < 4; j++) t4[j] = f2b(acc[dt][rg * 4 + j] * linv);
      *(u16x4*)(op + dt * 32 + rg * 8 + h2 * 4) = t4;
    }
}

extern "C" void kernel_launch(void* const* d_in, const int* in_sizes, int n_in,
                              void* d_out, int out_size, void* d_ws, size_t ws_size,
                              hipStream_t stream) {
  const float* x  = (const float*)d_in[0];
  const float* wq = (const float*)d_in[1];
  const float* wk = (const float*)d_in[2];
  const float* wv = (const float*)d_in[3];
  const float* wo = (const float*)d_in[4];

  char* ws = (char*)d_ws;
  u16* xb    = (u16*)ws;                                   // 4096x2048 bf16 (16.8 MB)
  u16* wqkvT = (u16*)(ws + 16777216);                      // 3072x2048 (12.6 MB)
  u16* woT   = (u16*)(ws + 16777216 + 12582912);           // 2048x2048 (8.4 MB)
  u16* qkv   = (u16*)(ws + 16777216 + 12582912 + 8388608); // 4096x3072 (25.2 MB)
  u16* attnb = xb;                                  // xb dead after gemm1
  u16* Vt    = wqkvT;                               // wqkvT region reused after gemm1
  u16* Kp    = (u16*)(ws + 16777216 + 4194304);
  u16* Vp    = (u16*)(ws + 16777216 + 8388608);

  // allow >64KB dynamic LDS for the pipelined GEMMs
  hipFuncSetAttribute(reinterpret_cast<const void*>(gemm_pipe<256>),
                      hipFuncAttributeMaxDynamicSharedMemorySize, 131072);
  hipFuncSetAttribute(reinterpret_cast<const void*>(gemm_pipe<128>),
                      hipFuncAttributeMaxDynamicSharedMemorySize, 98304);

  cast_x_kernel<<<8192, 256, 0, stream>>>(x, xb);
  dim3 tb(32, 8);
  transpose_cast<<<dim3(64, 64), tb, 0, stream>>>(wq, wqkvT, 2048, 2048);
  transpose_cast<<<dim3(16, 64), tb, 0, stream>>>(wk, wqkvT + (size_t)2048 * 2048, 512, 2048);
  transpose_cast<<<dim3(16, 64), tb, 0, stream>>>(wv, wqkvT + (size_t)2560 * 2048, 512, 2048);
  transpose_cast<<<dim3(64, 64), tb, 0, stream>>>(wo, woT, 2048, 2048);

  gemm_pipe<256><<<192, 512, 131072, stream>>>(xb, wqkvT, qkv, 4096, NQKV, 0);
  rope_kernel<<<4096, 256, 0, stream>>>(qkv);
  vtrans_kernel<<<512, 256, 0, stream>>>(qkv, Vt);
  kvpack_kernel<<<1024, 64, 0, stream>>>(qkv, Vt, Kp, Vp);
  attn_kernel<<<4096, 64, 0, stream>>>(qkv, Kp, Vp, attnb);
  gemm_pipe<128><<<256, 512, 98304, stream>>>(attnb, woT, d_out, 4096, 2048, 1);
}

// Round 10
// 281.282 us; speedup vs baseline: 1.7235x; 1.0164x over previous
//
#include <hip/hip_runtime.h>

#define S_LEN 2048
#define NH 32
#define NKV 8
#define HEADD 64
#define DMODEL 2048
#define NQKV 3072

typedef float f32x4 __attribute__((ext_vector_type(4)));
typedef float f32x16 __attribute__((ext_vector_type(16)));
typedef short s16x8 __attribute__((ext_vector_type(8)));
typedef int   i32x4 __attribute__((ext_vector_type(4)));
typedef unsigned short u16;
typedef u16 u16x4 __attribute__((ext_vector_type(4)));

__device__ __forceinline__ float b2f(u16 u) {
  unsigned int x = ((unsigned int)u) << 16;
  float f;
  __builtin_memcpy(&f, &x, 4);
  return f;
}
__device__ __forceinline__ u16 f2b(float f) {
  unsigned int x;
  __builtin_memcpy(&x, &f, 4);
  unsigned int r = x + 0x7fffu + ((x >> 16) & 1u);
  return (u16)(r >> 16);
}
__device__ __forceinline__ unsigned fbits(float f) {
  unsigned x; __builtin_memcpy(&x, &f, 4); return x;
}

// async 16B/lane global -> LDS (LDS dest is wave-uniform base + lane*16)
__device__ __forceinline__ void gload_lds16(const u16* g, u16* l) {
  __builtin_amdgcn_global_load_lds((const __attribute__((address_space(1))) void*)g,
                                   (__attribute__((address_space(3))) void*)l, 16, 0, 0);
}

template<int N> __device__ __forceinline__ void wait_vm() {
  asm volatile("s_waitcnt vmcnt(%0)" :: "n"(N) : "memory");
}

// ---------- x fp32 -> bf16 ----------
__global__ void cast_x_kernel(const float* __restrict__ src, u16* __restrict__ dst) {
  int i = (blockIdx.x * 256 + threadIdx.x) * 4;
  f32x4 v = *(const f32x4*)(src + i);
  u16x4 o;
  o[0] = f2b(v[0]); o[1] = f2b(v[1]); o[2] = f2b(v[2]); o[3] = f2b(v[3]);
  *(u16x4*)(dst + i) = o;
}

// ---------- transpose + cast: src (K x N fp32) -> dst (N x K bf16) ----------
__global__ void transpose_cast(const float* __restrict__ src, u16* __restrict__ dst, int N, int K) {
  __shared__ float tile[32][33];
  int n0 = blockIdx.x * 32, k0 = blockIdx.y * 32;
  int tx = threadIdx.x, ty = threadIdx.y;  // (32, 8)
#pragma unroll
  for (int i = 0; i < 32; i += 8)
    tile[ty + i][tx] = src[(size_t)(k0 + ty + i) * N + n0 + tx];
  __syncthreads();
#pragma unroll
  for (int i = 0; i < 32; i += 8)
    dst[(size_t)(n0 + ty + i) * K + k0 + tx] = f2b(tile[tx][ty + i]);
}

// ---------- GEMM: 256-row tiles, 8 waves, 4-buffer counted-vmcnt pipeline ----------
#define PIPE_BODY(Q, STAGE, VMN)                                                   \
  {                                                                                \
    wait_vm<VMN>();                                                                \
    __builtin_amdgcn_s_barrier();                                                  \
    __builtin_amdgcn_sched_barrier(0);                                             \
    if (STAGE) {                                                                   \
      u16* db = sm + ((Q + 3) & 3) * BUFE;                                         \
      gload_lds16(gA0, db + w * 1024);                                             \
      gload_lds16(gA1, db + w * 1024 + 512);                                       \
      if (BN == 256) {                                                             \
        gload_lds16(gB0, db + ABUF + w * 1024);                                    \
        gload_lds16(gB1, db + ABUF + w * 1024 + 512);                              \
      } else {                                                                     \
        gload_lds16(gB0, db + ABUF + w * 512);                                     \
      }                                                                            \
      gA0 += 32; gA1 += 32; gB0 += 32; if (BN == 256) gB1 += 32;                   \
    }                                                                              \
    const u16* bb = sm + Q * BUFE;                                                 \
    s16x8 af[8], bf[NF];                                                           \
    _Pragma("unroll") for (int i = 0; i < 8; i++)  af[i] = *(const s16x8*)(bb + aoff[i]); \
    _Pragma("unroll") for (int j = 0; j < NF; j++) bf[j] = *(const s16x8*)(bb + boff[j]); \
    __builtin_amdgcn_s_setprio(1);                                                 \
    _Pragma("unroll") for (int mi = 0; mi < 8; mi++)                               \
      _Pragma("unroll") for (int ni = 0; ni < NF; ni++)                            \
        acc[mi][ni] = __builtin_amdgcn_mfma_f32_16x16x32_bf16(af[mi], bf[ni], acc[mi][ni], 0, 0, 0); \
    __builtin_amdgcn_s_setprio(0);                                                 \
  }

template<int BN>
__global__ __launch_bounds__(512, 2) void gemm_pipe(
    const u16* __restrict__ A, const u16* __restrict__ Bt, void* __restrict__ Cout,
    int M, int N, int writeF32) {
  extern __shared__ __align__(16) u16 sm[];
  constexpr int NF   = BN / 64;
  constexpr int ABUF = 256 * 32;
  constexpr int BUFE = ABUF + BN * 32;
  constexpr int LPS  = 2 + BN / 128;

  int nb = N / BN;
  int nwg = (M >> 8) * nb;
  int cpx = nwg >> 3;
  int bid = ((int)blockIdx.x & 7) * cpx + ((int)blockIdx.x >> 3);  // XCD swizzle
  int m0 = (bid / nb) << 8;
  int n0 = (bid % nb) * BN;

  int tid = threadIdx.x;
  int lane = tid & 63;
  int w = tid >> 6;
  int wm8 = (w >> 2) << 7;
  int wn8 = (w & 3) * (BN / 4);
  int l15 = lane & 15;
  int quad = lane >> 4;

  int lr = lane >> 3;
  int lc = lane & 7;
  int slot = lc ^ lr;
  int kc8 = (slot & 3) << 3;
  const u16* gA0 = A + (size_t)(m0 + w * 32 + (lr << 1) + (slot >> 2)) * 2048 + kc8;
  const u16* gA1 = gA0 + (size_t)16 * 2048;
  const u16* gB0;
  const u16* gB1;
  if (BN == 256) {
    gB0 = Bt + (size_t)(n0 + w * 32 + (lr << 1) + (slot >> 2)) * 2048 + kc8;
    gB1 = gB0 + (size_t)16 * 2048;
  } else {
    gB0 = Bt + (size_t)(n0 + w * 16 + (lr << 1) + (slot >> 2)) * 2048 + kc8;
    gB1 = gB0;
  }

  int rb = l15 >> 1;
  int sl = (((((l15 & 1) << 2) | quad) ^ rb)) << 3;
  int rbase = rb * 64 + sl;
  int aoff[8], boff[NF];
#pragma unroll
  for (int i = 0; i < 8; i++) aoff[i] = wm8 * 32 + i * 512 + rbase;
#pragma unroll
  for (int j = 0; j < NF; j++) boff[j] = ABUF + wn8 * 32 + j * 512 + rbase;

  f32x4 acc[8][NF] = {};

#pragma unroll
  for (int pt = 0; pt < 3; pt++) {
    u16* db = sm + pt * BUFE;
    gload_lds16(gA0, db + w * 1024);
    gload_lds16(gA1, db + w * 1024 + 512);
    if (BN == 256) {
      gload_lds16(gB0, db + ABUF + w * 1024);
      gload_lds16(gB1, db + ABUF + w * 1024 + 512);
    } else {
      gload_lds16(gB0, db + ABUF + w * 512);
    }
    gA0 += 32; gA1 += 32; gB0 += 32; if (BN == 256) gB1 += 32;
  }

#pragma unroll 1
  for (int it = 0; it < 15; ++it) {
    PIPE_BODY(0, 1, 2 * LPS)
    PIPE_BODY(1, 1, 2 * LPS)
    PIPE_BODY(2, 1, 2 * LPS)
    PIPE_BODY(3, 1, 2 * LPS)
  }
  PIPE_BODY(0, 1, 2 * LPS)
  PIPE_BODY(1, 0, 2 * LPS)
  PIPE_BODY(2, 0, LPS)
  PIPE_BODY(3, 0, 0)

#pragma unroll
  for (int mi = 0; mi < 8; mi++)
#pragma unroll
    for (int ni = 0; ni < NF; ni++)
#pragma unroll
      for (int r = 0; r < 4; r++) {
        int row = m0 + wm8 + mi * 16 + (quad << 2) + r;
        int col = n0 + wn8 + ni * 16 + l15;
        float v = acc[mi][ni][r];
        if (writeF32) ((float*)Cout)[(size_t)row * N + col] = v;
        else ((u16*)Cout)[(size_t)row * N + col] = f2b(v);
      }
}

// ---------- in-place RoPE, vectorized (u16x4), LDS sincos dedup ----------
// 320 thr/block = 40 head-units (32 q + 8 k) x 8 d4-groups. Thread loads
// u16x4 pairs (d, d+32) -> 8B coalesced chunks instead of scalar u16.
__global__ void rope_kernel(u16* __restrict__ qkv) {
  __shared__ float cs_s[32], sn_s[32];
  int row = blockIdx.x;
  int s = row & (S_LEN - 1);
  u16* p = qkv + (size_t)row * NQKV;
  int t = threadIdx.x;
  if (t < 32) {
    float inv_freq = exp2f(-(float)t * (13.287712379549449f / 32.0f));
    float ang = (float)s * inv_freq;
    float sn, cs;
    sincosf(ang, &sn, &cs);
    cs_s[t] = cs;
    sn_s[t] = sn;
  }
  __syncthreads();
  const float QSCALE = 0.18033688011112042f;  // 0.125 * log2(e)
  int hu = t >> 3;           // 0..39
  int j = t & 7;             // d4-group
  int off = (hu < 32) ? hu * HEADD + j * 4 : DMODEL + (hu - 32) * HEADD + j * 4;
  float scale = (hu < 32) ? QSCALE : 1.0f;
  u16x4 a = *(const u16x4*)(p + off);
  u16x4 c = *(const u16x4*)(p + off + 32);
  u16x4 o1, o2;
#pragma unroll
  for (int jj = 0; jj < 4; jj++) {
    float x1 = b2f(a[jj]), x2 = b2f(c[jj]);
    float cs = cs_s[j * 4 + jj], sn = sn_s[j * 4 + jj];
    o1[jj] = f2b((x1 * cs - x2 * sn) * scale);
    o2[jj] = f2b((x1 * sn + x2 * cs) * scale);
  }
  *(u16x4*)(p + off) = o1;
  *(u16x4*)(p + off + 32) = o2;
}

// ---------- V transpose: qkv v-slice -> Vt[b][g][d=64][s=2048] ----------
__global__ void vtrans_kernel(const u16* __restrict__ qkv, u16* __restrict__ Vt) {
  __shared__ __align__(16) u16 tile[64][72];
  int bid = blockIdx.x;  // 2*8*32 = 512
  int st = bid & 31;
  int g  = (bid >> 5) & 7;
  int b  = bid >> 8;
  int tid = threadIdx.x;
  int r = tid >> 2;
  int c = (tid & 3) << 4;
  const u16* src = qkv + (size_t)(b * S_LEN + st * 64 + r) * NQKV + 2560 + g * 64 + c;
  *(i32x4*)&tile[r][c]     = *(const i32x4*)src;
  *(i32x4*)&tile[r][c + 8] = *(const i32x4*)(src + 8);
  __syncthreads();
  u16* dst = Vt + (size_t)((b * 8 + g) * 64 + r) * S_LEN + st * 64 + c;
  u16 tmp[16];
#pragma unroll
  for (int j = 0; j < 16; j++) tmp[j] = tile[c + j][r];
  *(i32x4*)dst       = *(i32x4*)&tmp[0];
  *(i32x4*)(dst + 8) = *(i32x4*)&tmp[8];
}

// ---------- pack K & V into fragment-ordered tiles ----------
__global__ __launch_bounds__(64) void kvpack_kernel(const u16* __restrict__ qkv,
                                                    const u16* __restrict__ Vt,
                                                    u16* __restrict__ Kp,
                                                    u16* __restrict__ Vp) {
  int bid = blockIdx.x;  // 1024 = bg*64 + kb
  int kb = bid & 63;
  int bg = bid >> 6;
  int g = bg & 7;
  int b = bg >> 3;
  int lane = threadIdx.x;
  int l31 = lane & 31;
  int h2 = lane >> 5;

  const u16* kq = qkv + (size_t)(b * S_LEN + kb * 32 + l31) * NQKV + DMODEL + g * 64 + h2 * 8;
  u16* kdst = Kp + ((size_t)bid * 4) * 512 + lane * 8;
#pragma unroll
  for (int t = 0; t < 4; t++)
    *(i32x4*)(kdst + t * 512) = *(const i32x4*)(kq + t * 16);

  const u16* vq = Vt + (size_t)(bg * 64 + l31) * S_LEN + kb * 32 + h2 * 8;
  u16* vdst = Vp + ((size_t)bid * 4) * 512 + lane * 8;
  *(i32x4*)(vdst)        = *(const i32x4*)vq;
  *(i32x4*)(vdst + 512)  = *(const i32x4*)(vq + 16);
  *(i32x4*)(vdst + 1024) = *(const i32x4*)(vq + (size_t)32 * S_LEN);
  *(i32x4*)(vdst + 1536) = *(const i32x4*)(vq + (size_t)32 * S_LEN + 16);
}

// ---------- MFMA flash attention: 4 heads/block share K/V via LDS ----------
// Block (b,g,qb): 4 waves, wave w owns head g*4+w. K/V tile (8KB) staged ONCE
// into LDS (4-buffer), gemm_pipe's proven counted-vmcnt + raw-barrier pattern.
// Final wait_vm<0> before exit: small-qb blocks otherwise end with outstanding
// global_load_lds writes into LDS that may be reassigned (UB -> corruption).
#define ASTEP(T, STG, VMN)                                                         \
  {                                                                                \
    wait_vm<VMN>();                                                                \
    __builtin_amdgcn_s_barrier();                                                  \
    __builtin_amdgcn_sched_barrier(0);                                             \
    if (STG) {                                                                     \
      int skb = (T) + 3;                                                           \
      u16* db = &kvbuf[((T) + 3) & 3][wv * 512];                                   \
      gload_lds16(kSrc + (size_t)skb * 2048, db);                                  \
      gload_lds16(vSrc + (size_t)skb * 2048, db + 2048);                           \
    }                                                                              \
    compute_t(T);                                                                  \
  }

__global__ __launch_bounds__(256) void attn_kernel(const u16* __restrict__ qkv,
                                                   const u16* __restrict__ Kp,
                                                   const u16* __restrict__ Vp,
                                                   u16* __restrict__ out) {
  __shared__ __align__(16) u16 kvbuf[4][4096];  // 4 bufs x (K 4KB + V 4KB)

  int bid = blockIdx.x;        // 1024 = qb-desc(64) * bg(16)
  int bg16 = bid & 15;         // b*8+g
  int qb = 63 - (bid >> 4);    // longest blocks launch first
  int g = bg16 & 7;
  int b = bg16 >> 3;
  int tid = threadIdx.x;
  int wv = tid >> 6;           // 0..3 -> rep index within group
  int lane = tid & 63;
  int l31 = lane & 31;
  int h2 = lane >> 5;
  int h = g * 4 + wv;
  int q0 = qb << 5;
  int nt = qb + 1;

  const u16* qp = qkv + (size_t)(b * S_LEN + q0 + l31) * NQKV + h * HEADD + h2 * 8;
  s16x8 qf[4];
#pragma unroll
  for (int t = 0; t < 4; t++) qf[t] = *(const s16x8*)(qp + t * 16);

  // per-wave staging source (wave stages 1KB slice of K and of V per tile)
  const u16* kSrc = Kp + ((size_t)bg16 * 64) * 2048 + wv * 512 + lane * 8;
  const u16* vSrc = Vp + ((size_t)bg16 * 64) * 2048 + wv * 512 + lane * 8;

  float l_i = 0.f;
  f32x16 acc[2] = {};

  auto compute_t = [&](int T) {
    const u16* bb = &kvbuf[T & 3][0];
    s16x8 kf[4], vf[4];
#pragma unroll
    for (int tt = 0; tt < 4; tt++)
      kf[tt] = *(const s16x8*)(bb + tt * 512 + lane * 8);

    f32x16 sc = {};
    __builtin_amdgcn_s_setprio(1);
#pragma unroll
    for (int tt = 0; tt < 4; tt++)
      sc = __builtin_amdgcn_mfma_f32_32x32x16_bf16(kf[tt], qf[tt], sc, 0, 0, 0);
    __builtin_amdgcn_s_setprio(0);

#pragma unroll
    for (int tt = 0; tt < 4; tt++)
      vf[tt] = *(const s16x8*)(bb + 2048 + tt * 512 + lane * 8);

    float sv[16];
#pragma unroll
    for (int j = 0; j < 16; j++) sv[j] = sc[j];

    if (T == qb) {
      int qg = q0 + l31;
#pragma unroll
      for (int j = 0; j < 16; j++) {
        int kg = qb * 32 + (j & 3) + ((j >> 2) << 3) + (h2 << 2);
        if (kg > qg) sv[j] = -1e30f;
      }
    }

    float e[16];
#pragma unroll
    for (int j = 0; j < 16; j++) e[j] = __builtin_amdgcn_exp2f(sv[j]);

    float ps = (((e[0] + e[1]) + (e[2] + e[3])) + ((e[4] + e[5]) + (e[6] + e[7])))
             + (((e[8] + e[9]) + (e[10] + e[11])) + ((e[12] + e[13]) + (e[14] + e[15])));
    ps += __shfl_xor(ps, 32);
    l_i += ps;

    unsigned Pk[8], Ex[8];
#pragma unroll
    for (int r = 0; r < 8; r++) {
      unsigned pk;
      asm("v_cvt_pk_bf16_f32 %0, %1, %2" : "=v"(pk) : "v"(e[2 * r]), "v"(e[2 * r + 1]));
      Pk[r] = pk;
    }
#pragma unroll
    for (int r = 0; r < 8; r++) Ex[r] = (unsigned)__shfl_xor((int)Pk[r], 32);

    unsigned B0u[4], B1u[4];
    B0u[0] = h2 ? Ex[2] : Pk[0];
    B0u[1] = h2 ? Ex[3] : Pk[1];
    B0u[2] = h2 ? Pk[2] : Ex[0];
    B0u[3] = h2 ? Pk[3] : Ex[1];
    B1u[0] = h2 ? Ex[6] : Pk[4];
    B1u[1] = h2 ? Ex[7] : Pk[5];
    B1u[2] = h2 ? Pk[6] : Ex[4];
    B1u[3] = h2 ? Pk[7] : Ex[5];
    s16x8 B0, B1;
    __builtin_memcpy(&B0, B0u, 16);
    __builtin_memcpy(&B1, B1u, 16);

    __builtin_amdgcn_s_setprio(1);
    acc[0] = __builtin_amdgcn_mfma_f32_32x32x16_bf16(vf[0], B0, acc[0], 0, 0, 0);
    acc[0] = __builtin_amdgcn_mfma_f32_32x32x16_bf16(vf[1], B1, acc[0], 0, 0, 0);
    acc[1] = __builtin_amdgcn_mfma_f32_32x32x16_bf16(vf[2], B0, acc[1], 0, 0, 0);
    acc[1] = __builtin_amdgcn_mfma_f32_32x32x16_bf16(vf[3], B1, acc[1], 0, 0, 0);
    __builtin_amdgcn_s_setprio(0);
  };

  // prologue: stage 3 tiles (dummy-clamp source for small qb so vmcnt math holds)
#pragma unroll
  for (int pt = 0; pt < 3; ++pt) {
    int skb = pt < nt ? pt : (nt - 1);
    u16* db = &kvbuf[pt][wv * 512];
    gload_lds16(kSrc + (size_t)skb * 2048, db);
    gload_lds16(vSrc + (size_t)skb * 2048, db + 2048);
  }

  int t = 0;
#pragma unroll 1
  for (; t + 3 < nt; ++t) ASTEP(t, 1, 4)
  // peel: outstanding 6 -> 4 -> 2 -> 0 (2 loads per staged tile)
  ASTEP(t, 0, 4); ++t;
  if (t < nt) { ASTEP(t, 0, 2); ++t; }
  if (t < nt) { ASTEP(t, 0, 0); }

  // drain any leftover prologue loads (small-qb blocks) before LDS is freed
  wait_vm<0>();

  float linv = 1.0f / l_i;
  u16* op = out + (size_t)(b * S_LEN + q0 + l31) * DMODEL + h * HEADD;
#pragma unroll
  for (int dt = 0; dt < 2; dt++)
#pragma unroll
    for (int rg = 0; rg < 4; rg++) {
      u16x4 t4;
#pragma unroll
      for (int j = 0; j < 4; j++) t4[j] = f2b(acc[dt][rg * 4 + j] * linv);
      *(u16x4*)(op + dt * 32 + rg * 8 + h2 * 4) = t4;
    }
}

extern "C" void kernel_launch(void* const* d_in, const int* in_sizes, int n_in,
                              void* d_out, int out_size, void* d_ws, size_t ws_size,
                              hipStream_t stream) {
  const float* x  = (const float*)d_in[0];
  const float* wq = (const float*)d_in[1];
  const float* wk = (const float*)d_in[2];
  const float* wv = (const float*)d_in[3];
  const float* wo = (const float*)d_in[4];

  char* ws = (char*)d_ws;
  u16* xb    = (u16*)ws;                                   // 4096x2048 bf16 (16.8 MB)
  u16* wqkvT = (u16*)(ws + 16777216);                      // 3072x2048 (12.6 MB)
  u16* woT   = (u16*)(ws + 16777216 + 12582912);           // 2048x2048 (8.4 MB)
  u16* qkv   = (u16*)(ws + 16777216 + 12582912 + 8388608); // 4096x3072 (25.2 MB)
  u16* attnb = xb;                                  // xb dead after gemm1
  u16* Vt    = wqkvT;                               // wqkvT region reused after gemm1
  u16* Kp    = (u16*)(ws + 16777216 + 4194304);
  u16* Vp    = (u16*)(ws + 16777216 + 8388608);

  // allow >64KB dynamic LDS for the pipelined GEMMs
  hipFuncSetAttribute(reinterpret_cast<const void*>(gemm_pipe<256>),
                      hipFuncAttributeMaxDynamicSharedMemorySize, 131072);
  hipFuncSetAttribute(reinterpret_cast<const void*>(gemm_pipe<128>),
                      hipFuncAttributeMaxDynamicSharedMemorySize, 98304);

  cast_x_kernel<<<8192, 256, 0, stream>>>(x, xb);
  dim3 tb(32, 8);
  transpose_cast<<<dim3(64, 64), tb, 0, stream>>>(wq, wqkvT, 2048, 2048);
  transpose_cast<<<dim3(16, 64), tb, 0, stream>>>(wk, wqkvT + (size_t)2048 * 2048, 512, 2048);
  transpose_cast<<<dim3(16, 64), tb, 0, stream>>>(wv, wqkvT + (size_t)2560 * 2048, 512, 2048);
  transpose_cast<<<dim3(64, 64), tb, 0, stream>>>(wo, woT, 2048, 2048);

  gemm_pipe<256><<<192, 512, 131072, stream>>>(xb, wqkvT, qkv, 4096, NQKV, 0);
  rope_kernel<<<4096, 320, 0, stream>>>(qkv);
  vtrans_kernel<<<512, 256, 0, stream>>>(qkv, Vt);
  kvpack_kernel<<<1024, 64, 0, stream>>>(qkv, Vt, Kp, Vp);
  attn_kernel<<<1024, 256, 0, stream>>>(qkv, Kp, Vp, attnb);
  gemm_pipe<128><<<256, 512, 98304, stream>>>(attnb, woT, d_out, 4096, 2048, 1);
}